// Round 10
// baseline (579.617 us; speedup 1.0000x reference)
//
#include <hip/hip_runtime.h>

#define N_NODES 10000
#define N_EDGES 160000
#define BATCH   8
#define D       128
#define TWO_D   256
#define EPS     1e-5f
#define ETILE   32
#define TPB_E   8     // edge tiles per block (persistent loop)
#define TPB_N   2     // node tiles per block (more blocks -> better tail)

typedef _Float16 f16x8  __attribute__((ext_vector_type(8)));
typedef float    f32x16 __attribute__((ext_vector_type(16)));
typedef int      intx4  __attribute__((ext_vector_type(4)));

// ---------------- generic zero ----------------
__global__ void zero_kernel(float4* __restrict__ p, long long n4) {
    long long idx    = (long long)blockIdx.x * blockDim.x + threadIdx.x;
    long long stride = (long long)gridDim.x * blockDim.x;
    const float4 z = {0.f, 0.f, 0.f, 0.f};
    for (long long i = idx; i < n4; i += stride) p[i] = z;
}

// ---------------- W prep: f16 images in B-fragment order ----------------
// img_m[g*128 + o] (16B = 8 f16) = Wm[o][8g .. 8g+7],  g in [0,32)  (64 KB)
// img_n at +65536 likewise for Wn.
__global__ void prep_w(const float* __restrict__ Wm, const float* __restrict__ Wn,
                       unsigned char* __restrict__ img) {
    int t = blockIdx.x * blockDim.x + threadIdx.x;
    if (t >= 4096) return;
    int g = t >> 7, o = t & 127;
    f16x8 vm, vn;
#pragma unroll
    for (int j = 0; j < 8; ++j) {
        vm[j] = (_Float16)Wm[o * TWO_D + 8 * g + j];
        vn[j] = (_Float16)Wn[o * TWO_D + 8 * g + j];
    }
    ((f16x8*)img)[t]           = vm;
    ((f16x8*)(img + 65536))[t] = vn;
}

// ---------------- counting sort of edges by receiver (proven) ----------
__global__ void hist_kernel(const int* __restrict__ recv, int* __restrict__ counts) {
    int e = blockIdx.x * blockDim.x + threadIdx.x;
    if (e < N_EDGES) atomicAdd(&counts[recv[e]], 1);
}

__global__ __launch_bounds__(1024)
void scan_kernel(const int* __restrict__ counts, int* __restrict__ cursor) {
    __shared__ int tmp[1024];
    int t = threadIdx.x;
    int local[10];
    int s = 0;
#pragma unroll
    for (int j = 0; j < 10; ++j) {
        int idx = t * 10 + j;
        int v = (idx < N_NODES) ? counts[idx] : 0;
        local[j] = s; s += v;
    }
    tmp[t] = s; __syncthreads();
    for (int off = 1; off < 1024; off <<= 1) {
        int v = tmp[t];
        int add = (t >= off) ? tmp[t - off] : 0;
        __syncthreads();
        tmp[t] = v + add;
        __syncthreads();
    }
    int base = (t > 0) ? tmp[t - 1] : 0;
#pragma unroll
    for (int j = 0; j < 10; ++j) {
        int idx = t * 10 + j;
        if (idx < N_NODES) cursor[idx] = base + local[j];
    }
}

__global__ void scatter_kernel(const int* __restrict__ recv, int* __restrict__ cursor,
                               int* __restrict__ perm) {
    int e = blockIdx.x * blockDim.x + threadIdx.x;
    if (e < N_EDGES) {
        int p = atomicAdd(&cursor[recv[e]], 1);
        perm[p] = e;
    }
}

// ---------------- MFMA edge kernel v5 (persistent + T14 prefetch) ----------
// 1-D grid 5000 blocks; batch = bid & 7 (XCD-pinned: FETCH 270->182 MB, R9).
// 256 threads = 4 waves; wave w owns outs [32w,32w+32), W f16 frags pinned
// in regs (AGPR-resident via asm pin, verified R9). Persistent loop over
// TPB_E receiver-sorted 32-edge tiles, SOFTWARE-PIPELINED: tile it+1's
// gather (perm->recv->rows, ~3 dependent L2 latencies) is issued into
// REGISTERS right after tile it's staging barrier and consumed one
// iteration later -> latency hides under k-loop+LN+scatter.
__global__ __launch_bounds__(256, 4)
void edge_mfma(const float* __restrict__ nodes,
               const unsigned char* __restrict__ wimg,
               const float* __restrict__ bm,
               const float* __restrict__ g1,
               const float* __restrict__ b1,
               const int*   __restrict__ senders,
               const int*   __restrict__ receivers,
               const int*   __restrict__ perm,
               float* __restrict__ inbox) {
    // Xh [0,16K), Xl [16K,32K); msg fp32[32][132] overlays @16384..33280
    __shared__ __align__(16) unsigned char s_lds[33280];
    __shared__ int   s_recv[ETILE];
    __shared__ float s_mu[ETILE];
    __shared__ float s_rs[ETILE];

    const int tid    = threadIdx.x;
    const int b      = blockIdx.x & 7;          // batch == XCD (round-robin)
    const int grp    = blockIdx.x >> 3;         // tile group within batch
    const int w      = tid >> 6;
    const int l      = tid & 63;
    const int lane31 = l & 31;
    const int hiG    = l >> 5;
    const int o      = w * 32 + lane31;         // this lane's output column

    // ---- W fragments -> registers, ONCE, pinned (AGPR-resident, R9) ----
    intx4 wfi[16];
    {
        const intx4* img = (const intx4*)wimg;
#pragma unroll
        for (int ks = 0; ks < 16; ++ks)
            wfi[ks] = img[(2 * ks + hiG) * 128 + o];
#pragma unroll
        for (int ks = 0; ks < 16; ++ks)
            asm volatile("" : "+v"(wfi[ks]));   // opaque def: must stay resident
    }
    const float bmv = bm[o];
    const int   col  = tid & 127;
    const int   half = tid >> 7;
    const float gv = g1[col], bv = b1[col];
    float* const abase = inbox + (size_t)b * N_NODES * D + col;

    const int i  = tid & 31;   // edge slot
    const int q8 = tid >> 5;   // k chunk [32*q8, 32*q8+32)
    f16x8* const Xh  = (f16x8*)s_lds;
    f16x8* const Xl  = (f16x8*)(s_lds + 16384);
    float* const msg = (float*)(s_lds + 16384);

    // ---- prologue: prefetch tile 0 gather into registers ----
    int    rcur;
    float4 pa[4], pb[4];
    {
        const int e0 = grp * TPB_E * ETILE;
        const int pe = perm[e0 + i];
        rcur = (q8 < 4) ? receivers[pe] : senders[pe];
        const float* row = nodes + ((size_t)b * N_NODES + rcur) * D + (q8 & 3) * 32;
#pragma unroll
        for (int j = 0; j < 4; ++j) {
            pa[j] = *(const float4*)(row + 8 * j);
            pb[j] = *(const float4*)(row + 8 * j + 4);
        }
    }

    for (int it = 0; it < TPB_E; ++it) {
        // ---- write phase: cvt prefetched rows -> f16 hi/lo LDS ----
        if (q8 == 0) s_recv[i] = rcur;
#pragma unroll
        for (int j = 0; j < 4; ++j) {
            const float xs[8] = {pa[j].x, pa[j].y, pa[j].z, pa[j].w,
                                 pb[j].x, pb[j].y, pb[j].z, pb[j].w};
            f16x8 h, lo;
#pragma unroll
            for (int u = 0; u < 8; ++u) {
                h[u]  = (_Float16)xs[u];
                lo[u] = (_Float16)(xs[u] - (float)h[u]);
            }
            const int g = 4 * q8 + j;
            Xh[g * 32 + i] = h;
            Xl[g * 32 + i] = lo;
        }
        __syncthreads();

        // ---- issue next tile's gather (hides under k-loop+LN+scatter) ----
        if (it + 1 < TPB_E) {
            const int e0n = (grp * TPB_E + it + 1) * ETILE;
            const int pe  = perm[e0n + i];
            rcur = (q8 < 4) ? receivers[pe] : senders[pe];
            const float* row = nodes + ((size_t)b * N_NODES + rcur) * D + (q8 & 3) * 32;
#pragma unroll
            for (int j = 0; j < 4; ++j) {
                pa[j] = *(const float4*)(row + 8 * j);
                pb[j] = *(const float4*)(row + 8 * j + 4);
            }
        }

        // ---- k-loop: pure LDS-read + MFMA (W already in regs) ----
        f32x16 acc;
#pragma unroll
        for (int r = 0; r < 16; ++r) acc[r] = 0.f;
        __builtin_amdgcn_s_setprio(1);
#pragma unroll
        for (int ks = 0; ks < 16; ++ks) {
            const f16x8 ah = Xh[(2 * ks + hiG) * 32 + lane31];
            const f16x8 al = Xl[(2 * ks + hiG) * 32 + lane31];
            const f16x8 wk = __builtin_bit_cast(f16x8, wfi[ks]);
            acc = __builtin_amdgcn_mfma_f32_32x32x16_f16(ah, wk, acc, 0, 0, 0);
            acc = __builtin_amdgcn_mfma_f32_32x32x16_f16(al, wk, acc, 0, 0, 0);
        }
        __builtin_amdgcn_s_setprio(0);
        __syncthreads();   // X reads done; msg overlays Xl

        // ---- bias + raw messages -> msg[32][132] ----
#pragma unroll
        for (int r = 0; r < 16; ++r) {
            const int m = (r & 3) + 8 * (r >> 2) + 4 * hiG;
            msg[m * 132 + o] = acc[r] + bmv;
        }
        __syncthreads();

        // ---- LN stats, single pass (8 threads per row) ----
        {
            const int m = tid >> 3, c0 = tid & 7;
            float s = 0.f, s2 = 0.f;
#pragma unroll
            for (int i2 = 0; i2 < 16; ++i2) {
                const float v = msg[m * 132 + c0 + 8 * i2];
                s += v; s2 += v * v;
            }
            s  += __shfl_xor(s, 1, 64);  s  += __shfl_xor(s, 2, 64);  s  += __shfl_xor(s, 4, 64);
            s2 += __shfl_xor(s2, 1, 64); s2 += __shfl_xor(s2, 2, 64); s2 += __shfl_xor(s2, 4, 64);
            if (c0 == 0) {
                const float mu  = s * (1.f / 128.f);
                const float var = s2 * (1.f / 128.f) - mu * mu;
                s_mu[m] = mu;
                s_rs[m] = rsqrtf(var + EPS);
            }
        }
        __syncthreads();

        // ---- scatter: inline LN + run-merge over sorted receivers ----
        {
            int prev = -1; float accu = 0.f;
#pragma unroll
            for (int e = 0; e < 16; ++e) {
                const int ee = half * 16 + e;
                const int r  = s_recv[ee];
                const float val = (msg[ee * 132 + col] - s_mu[ee]) * s_rs[ee] * gv + bv;
                if (r != prev) {
                    if (prev >= 0) atomicAdd(abase + (size_t)prev * D, accu);
                    prev = r; accu = val;
                } else {
                    accu += val;
                }
            }
            if (prev >= 0) atomicAdd(abase + (size_t)prev * D, accu);
        }
        __syncthreads();   // protect X/msg before next tile's write phase
    }
}

// ---------------- MFMA node kernel v5 (persistent + prefetch) ------------
__global__ __launch_bounds__(256, 4)
void node_mfma(const float* __restrict__ nodes,
               const float* __restrict__ inbox,
               const unsigned char* __restrict__ wimg,
               const float* __restrict__ bn,
               const float* __restrict__ g2,
               const float* __restrict__ b2,
               float* __restrict__ out) {
    __shared__ __align__(16) unsigned char s_lds[33280];
    __shared__ float s_mu[ETILE];
    __shared__ float s_rs[ETILE];

    const int tid    = threadIdx.x;
    const int b      = blockIdx.x & 7;
    const int grp    = blockIdx.x >> 3;
    const int w      = tid >> 6;
    const int l      = tid & 63;
    const int lane31 = l & 31;
    const int hiG    = l >> 5;
    const int o      = w * 32 + lane31;

    intx4 wfi[16];
    {
        const intx4* img = (const intx4*)wimg;
#pragma unroll
        for (int ks = 0; ks < 16; ++ks)
            wfi[ks] = img[(2 * ks + hiG) * 128 + o];
#pragma unroll
        for (int ks = 0; ks < 16; ++ks)
            asm volatile("" : "+v"(wfi[ks]));
    }
    const float bnv = bn[o];
    const int   col  = tid & 127;
    const int   half = tid >> 7;
    const float gv = g2[col], bv = b2[col];

    const int i  = tid & 31;
    const int q8 = tid >> 5;
    f16x8* const Xh  = (f16x8*)s_lds;
    f16x8* const Xl  = (f16x8*)(s_lds + 16384);
    float* const msg = (float*)(s_lds + 16384);

    const int NTILES = (N_NODES + ETILE - 1) / ETILE;   // 313

    // prologue prefetch (tile grp*TPB_N always < NTILES for launched grid)
    float4 pa[4], pb[4];
    {
        int n = grp * TPB_N * ETILE + i;
        if (n >= N_NODES) n = N_NODES - 1;
        const float* row = ((q8 < 4) ? nodes : inbox)
                         + ((size_t)b * N_NODES + n) * D + (q8 & 3) * 32;
#pragma unroll
        for (int j = 0; j < 4; ++j) {
            pa[j] = *(const float4*)(row + 8 * j);
            pb[j] = *(const float4*)(row + 8 * j + 4);
        }
    }

    for (int it = 0; it < TPB_N; ++it) {
        const int tile = grp * TPB_N + it;
        if (tile >= NTILES) break;                       // uniform per block
        const int n0 = tile * ETILE;

#pragma unroll
        for (int j = 0; j < 4; ++j) {
            const float xs[8] = {pa[j].x, pa[j].y, pa[j].z, pa[j].w,
                                 pb[j].x, pb[j].y, pb[j].z, pb[j].w};
            f16x8 h, lo;
#pragma unroll
            for (int u = 0; u < 8; ++u) {
                h[u]  = (_Float16)xs[u];
                lo[u] = (_Float16)(xs[u] - (float)h[u]);
            }
            const int g = 4 * q8 + j;
            Xh[g * 32 + i] = h;
            Xl[g * 32 + i] = lo;
        }
        __syncthreads();

        if (it + 1 < TPB_N && tile + 1 < NTILES) {
            int n = (tile + 1) * ETILE + i;
            if (n >= N_NODES) n = N_NODES - 1;
            const float* row = ((q8 < 4) ? nodes : inbox)
                             + ((size_t)b * N_NODES + n) * D + (q8 & 3) * 32;
#pragma unroll
            for (int j = 0; j < 4; ++j) {
                pa[j] = *(const float4*)(row + 8 * j);
                pb[j] = *(const float4*)(row + 8 * j + 4);
            }
        }

        f32x16 acc;
#pragma unroll
        for (int r = 0; r < 16; ++r) acc[r] = 0.f;
        __builtin_amdgcn_s_setprio(1);
#pragma unroll
        for (int ks = 0; ks < 16; ++ks) {
            const f16x8 ah = Xh[(2 * ks + hiG) * 32 + lane31];
            const f16x8 al = Xl[(2 * ks + hiG) * 32 + lane31];
            const f16x8 wk = __builtin_bit_cast(f16x8, wfi[ks]);
            acc = __builtin_amdgcn_mfma_f32_32x32x16_f16(ah, wk, acc, 0, 0, 0);
            acc = __builtin_amdgcn_mfma_f32_32x32x16_f16(al, wk, acc, 0, 0, 0);
        }
        __builtin_amdgcn_s_setprio(0);
        __syncthreads();

#pragma unroll
        for (int r = 0; r < 16; ++r) {
            const int m = (r & 3) + 8 * (r >> 2) + 4 * hiG;
            msg[m * 132 + o] = acc[r] + bnv;
        }
        __syncthreads();

        {
            const int m = tid >> 3, c0 = tid & 7;
            float s = 0.f, s2 = 0.f;
#pragma unroll
            for (int i2 = 0; i2 < 16; ++i2) {
                const float v = msg[m * 132 + c0 + 8 * i2];
                s += v; s2 += v * v;
            }
            s  += __shfl_xor(s, 1, 64);  s  += __shfl_xor(s, 2, 64);  s  += __shfl_xor(s, 4, 64);
            s2 += __shfl_xor(s2, 1, 64); s2 += __shfl_xor(s2, 2, 64); s2 += __shfl_xor(s2, 4, 64);
            if (c0 == 0) {
                const float mu  = s * (1.f / 128.f);
                const float var = s2 * (1.f / 128.f) - mu * mu;
                s_mu[m] = mu;
                s_rs[m] = rsqrtf(var + EPS);
            }
        }
        __syncthreads();

        {
#pragma unroll
            for (int e = 0; e < 16; ++e) {
                const int ee = half * 16 + e;
                const int n  = n0 + ee;
                if (n < N_NODES) {
                    out[((size_t)b * N_NODES + n) * D + col] =
                        (msg[ee * 132 + col] - s_mu[ee]) * s_rs[ee] * gv + bv;
                }
            }
        }
        __syncthreads();
    }
}

// ---------------- fp32 fallback kernels (proven R2, no workspace) ---------
__global__ __launch_bounds__(256, 2)
void edge_kernel(const float* __restrict__ nodes,
                 const float* __restrict__ Wm,
                 const float* __restrict__ bm,
                 const float* __restrict__ g1,
                 const float* __restrict__ b1,
                 const int*   __restrict__ senders,
                 const int*   __restrict__ receivers,
                 float* __restrict__ inbox) {
    __shared__ __align__(16) float ldsE[TWO_D][36];
    __shared__ __align__(16) float ldsW[64 * D];
    const int tid = threadIdx.x;
    const int b   = blockIdx.y;
    const int e0  = blockIdx.x * 32;
    const float* nb = nodes + (size_t)b * N_NODES * D;
    {
        const int i = tid >> 3, q0 = tid & 7, e = e0 + i;
        const float* rowR = nb + (size_t)receivers[e] * D;
        const float* rowS = nb + (size_t)senders[e] * D;
#pragma unroll
        for (int j = 0; j < 8; ++j) {
            const int k = (j * 8 + q0) * 4;
            const float4 v = (k < D) ? *(const float4*)(rowR + k)
                                     : *(const float4*)(rowS + (k - D));
            ldsE[k + 0][i] = v.x; ldsE[k + 1][i] = v.y;
            ldsE[k + 2][i] = v.z; ldsE[k + 3][i] = v.w;
        }
    }
    float acc[4][4];
#pragma unroll
    for (int a = 0; a < 4; ++a)
#pragma unroll
        for (int c = 0; c < 4; ++c) acc[a][c] = 0.0f;
    const int og = tid & 31, eg = tid >> 5;
    for (int kt = 0; kt < 4; ++kt) {
        __syncthreads();
        {
            const int oo = tid >> 1, half = tid & 1;
            const float* wrow = Wm + oo * TWO_D + kt * 64 + half * 32;
#pragma unroll
            for (int j = 0; j < 8; ++j) {
                const float4 w4 = *(const float4*)(wrow + j * 4);
                const int k2 = half * 32 + j * 4;
                ldsW[(k2 + 0) * D + oo] = w4.x; ldsW[(k2 + 1) * D + oo] = w4.y;
                ldsW[(k2 + 2) * D + oo] = w4.z; ldsW[(k2 + 3) * D + oo] = w4.w;
            }
        }
        __syncthreads();
#pragma unroll 4
        for (int k2 = 0; k2 < 64; ++k2) {
            const float4 wv = *(const float4*)&ldsW[k2 * D + 4 * og];
            const float4 xv = *(const float4*)&ldsE[kt * 64 + k2][4 * eg];
            const float wa[4] = {wv.x, wv.y, wv.z, wv.w};
            const float xa[4] = {xv.x, xv.y, xv.z, xv.w};
#pragma unroll
            for (int a = 0; a < 4; ++a)
#pragma unroll
                for (int c = 0; c < 4; ++c)
                    acc[a][c] = fmaf(xa[a], wa[c], acc[a][c]);
        }
    }
    const float4 bmv = *(const float4*)&bm[4 * og];
    const float4 g1v = *(const float4*)&g1[4 * og];
    const float4 b1v = *(const float4*)&b1[4 * og];
#pragma unroll
    for (int a = 0; a < 4; ++a) {
        acc[a][0] += bmv.x; acc[a][1] += bmv.y;
        acc[a][2] += bmv.z; acc[a][3] += bmv.w;
    }
    float mu[4], rs[4];
#pragma unroll
    for (int a = 0; a < 4; ++a) {
        float s = acc[a][0] + acc[a][1] + acc[a][2] + acc[a][3];
#pragma unroll
        for (int m = 16; m >= 1; m >>= 1) s += __shfl_xor(s, m, 64);
        mu[a] = s * (1.0f / 128.0f);
        const float d0 = acc[a][0] - mu[a], d1 = acc[a][1] - mu[a];
        const float d2 = acc[a][2] - mu[a], d3 = acc[a][3] - mu[a];
        float q = d0 * d0 + d1 * d1 + d2 * d2 + d3 * d3;
#pragma unroll
        for (int m = 16; m >= 1; m >>= 1) q += __shfl_xor(q, m, 64);
        rs[a] = rsqrtf(q * (1.0f / 128.0f) + EPS);
    }
#pragma unroll
    for (int a = 0; a < 4; ++a) {
        const int e = e0 + 4 * eg + a;
        const int r = receivers[e];
        float* dst = inbox + ((size_t)b * N_NODES + r) * D + 4 * og;
        atomicAdd(dst + 0, (acc[a][0] - mu[a]) * rs[a] * g1v.x + b1v.x);
        atomicAdd(dst + 1, (acc[a][1] - mu[a]) * rs[a] * g1v.y + b1v.y);
        atomicAdd(dst + 2, (acc[a][2] - mu[a]) * rs[a] * g1v.z + b1v.z);
        atomicAdd(dst + 3, (acc[a][3] - mu[a]) * rs[a] * g1v.w + b1v.w);
    }
}

__global__ __launch_bounds__(256, 2)
void node_kernel(const float* __restrict__ nodes,
                 const float* __restrict__ inbox,
                 const float* __restrict__ Wn,
                 const float* __restrict__ bn,
                 const float* __restrict__ g2,
                 const float* __restrict__ b2,
                 float* __restrict__ out) {
    __shared__ __align__(16) float ldsE[TWO_D][36];
    __shared__ __align__(16) float ldsW[64 * D];
    const int tid = threadIdx.x;
    const int b   = blockIdx.y;
    const int n0  = blockIdx.x * 32;
    {
        const int i = tid >> 3, q0 = tid & 7;
        int n = n0 + i;
        if (n >= N_NODES) n = N_NODES - 1;
        const float* rowN = nodes + ((size_t)b * N_NODES + n) * D;
        const float* rowI = inbox + ((size_t)b * N_NODES + n) * D;
#pragma unroll
        for (int j = 0; j < 8; ++j) {
            const int k = (j * 8 + q0) * 4;
            const float4 v = (k < D) ? *(const float4*)(rowN + k)
                                     : *(const float4*)(rowI + (k - D));
            ldsE[k + 0][i] = v.x; ldsE[k + 1][i] = v.y;
            ldsE[k + 2][i] = v.z; ldsE[k + 3][i] = v.w;
        }
    }
    float acc[4][4];
#pragma unroll
    for (int a = 0; a < 4; ++a)
#pragma unroll
        for (int c = 0; c < 4; ++c) acc[a][c] = 0.0f;
    const int og = tid & 31, eg = tid >> 5;
    for (int kt = 0; kt < 4; ++kt) {
        __syncthreads();
        {
            const int oo = tid >> 1, half = tid & 1;
            const float* wrow = Wn + oo * TWO_D + kt * 64 + half * 32;
#pragma unroll
            for (int j = 0; j < 8; ++j) {
                const float4 w4 = *(const float4*)(wrow + j * 4);
                const int k2 = half * 32 + j * 4;
                ldsW[(k2 + 0) * D + oo] = w4.x; ldsW[(k2 + 1) * D + oo] = w4.y;
                ldsW[(k2 + 2) * D + oo] = w4.z; ldsW[(k2 + 3) * D + oo] = w4.w;
            }
        }
        __syncthreads();
#pragma unroll 4
        for (int k2 = 0; k2 < 64; ++k2) {
            const float4 wv = *(const float4*)&ldsW[k2 * D + 4 * og];
            const float4 xv = *(const float4*)&ldsE[kt * 64 + k2][4 * eg];
            const float wa[4] = {wv.x, wv.y, wv.z, wv.w};
            const float xa[4] = {xv.x, xv.y, xv.z, xv.w};
#pragma unroll
            for (int a = 0; a < 4; ++a)
#pragma unroll
                for (int c = 0; c < 4; ++c)
                    acc[a][c] = fmaf(xa[a], wa[c], acc[a][c]);
        }
    }
    const float4 bnv = *(const float4*)&bn[4 * og];
    const float4 g2v = *(const float4*)&g2[4 * og];
    const float4 b2v = *(const float4*)&b2[4 * og];
#pragma unroll
    for (int a = 0; a < 4; ++a) {
        acc[a][0] += bnv.x; acc[a][1] += bnv.y;
        acc[a][2] += bnv.z; acc[a][3] += bnv.w;
    }
    float mu[4], rs[4];
#pragma unroll
    for (int a = 0; a < 4; ++a) {
        float s = acc[a][0] + acc[a][1] + acc[a][2] + acc[a][3];
#pragma unroll
        for (int m = 16; m >= 1; m >>= 1) s += __shfl_xor(s, m, 64);
        mu[a] = s * (1.0f / 128.0f);
        const float d0 = acc[a][0] - mu[a], d1 = acc[a][1] - mu[a];
        const float d2 = acc[a][2] - mu[a], d3 = acc[a][3] - mu[a];
        float q = d0 * d0 + d1 * d1 + d2 * d2 + d3 * d3;
#pragma unroll
        for (int m = 16; m >= 1; m >>= 1) q += __shfl_xor(q, m, 64);
        rs[a] = rsqrtf(q * (1.0f / 128.0f) + EPS);
    }
#pragma unroll
    for (int a = 0; a < 4; ++a) {
        const int n = n0 + 4 * eg + a;
        if (n < N_NODES) {
            float4 o4;
            o4.x = (acc[a][0] - mu[a]) * rs[a] * g2v.x + b2v.x;
            o4.y = (acc[a][1] - mu[a]) * rs[a] * g2v.y + b2v.y;
            o4.z = (acc[a][2] - mu[a]) * rs[a] * g2v.z + b2v.z;
            o4.w = (acc[a][3] - mu[a]) * rs[a] * g2v.w + b2v.w;
            *(float4*)(out + ((size_t)b * N_NODES + n) * D + 4 * og) = o4;
        }
    }
}

// ---------------------------------------------------------------------------
extern "C" void kernel_launch(void* const* d_in, const int* in_sizes, int n_in,
                              void* d_out, int out_size, void* d_ws, size_t ws_size,
                              hipStream_t stream) {
    const float* nodes     = (const float*)d_in[0];
    const float* Wm        = (const float*)d_in[1];
    const float* bm        = (const float*)d_in[2];
    const float* g1        = (const float*)d_in[3];
    const float* b1        = (const float*)d_in[4];
    const float* Wn        = (const float*)d_in[5];
    const float* bn        = (const float*)d_in[6];
    const float* g2        = (const float*)d_in[7];
    const float* b2        = (const float*)d_in[8];
    const int*   senders   = (const int*)d_in[9];
    const int*   receivers = (const int*)d_in[10];
    float*       out       = (float*)d_out;

    const long long inbox_n = (long long)BATCH * N_NODES * D;   // 10.24M floats
    // ws: [0,64K) img_m | [64K,128K) img_n | [128K,+720K) sort | [1M,+41MB) inbox
    const size_t SCRATCH_NEED = 131072 + 720128;

    if (d_ws != nullptr && ws_size >= SCRATCH_NEED) {
        unsigned char* wsb  = (unsigned char*)d_ws;
        unsigned char* wimg = wsb;                 // img_m @0, img_n @65536
        int* ints   = (int*)(wsb + 131072);
        int* counts = ints;            // 10000 (16B aligned)
        int* cursor = ints + 10016;    // 10000
        int* perm   = ints + 20032;    // 160000
        float* inbox = (ws_size >= (size_t)1048576 + (size_t)inbox_n * 4)
                           ? (float*)(wsb + 1048576) : out;

        zero_kernel<<<dim3(10),   dim3(256), 0, stream>>>((float4*)counts, 2500);
        zero_kernel<<<dim3(2048), dim3(256), 0, stream>>>((float4*)inbox, inbox_n / 4);
        prep_w<<<dim3(16), dim3(256), 0, stream>>>(Wm, Wn, wimg);
        hist_kernel<<<dim3(625), dim3(256), 0, stream>>>(receivers, counts);
        scan_kernel<<<dim3(1), dim3(1024), 0, stream>>>(counts, cursor);
        scatter_kernel<<<dim3(625), dim3(256), 0, stream>>>(receivers, cursor, perm);

        // 1-D grid, batch = bid & 7 -> XCD-pinned batches (5000 blocks)
        edge_mfma<<<dim3(N_EDGES / ETILE / TPB_E * BATCH), dim3(256), 0, stream>>>(
            nodes, wimg, bm, g1, b1, senders, receivers, perm, inbox);

        // 313 node tiles -> 157 groups x 8 batches = 1256 blocks
        const int ntiles = (N_NODES + ETILE - 1) / ETILE;
        node_mfma<<<dim3((ntiles + TPB_N - 1) / TPB_N * BATCH), dim3(256), 0, stream>>>(
            nodes, inbox, wimg + 65536, bn, g2, b2, out);
    } else {
        // proven fp32 fallback (no workspace needed)
        float* inbox = out;
        zero_kernel<<<dim3(2048), dim3(256), 0, stream>>>((float4*)inbox, inbox_n / 4);
        edge_kernel<<<dim3(N_EDGES / 32, BATCH), dim3(256), 0, stream>>>(
            nodes, Wm, bm, g1, b1, senders, receivers, inbox);
        node_kernel<<<dim3((N_NODES + 31) / 32, BATCH), dim3(256), 0, stream>>>(
            nodes, inbox, Wn, bn, g2, b2, out);
    }
}

// Round 12
// 412.442 us; speedup vs baseline: 1.4053x; 1.4053x over previous
//
#include <hip/hip_runtime.h>

#define N_NODES 10000
#define N_EDGES 160000
#define BATCH   8
#define D       128
#define TWO_D   256
#define EPS     1e-5f
#define ETILE   32
#define TPB_E   8     // edge tiles per block (persistent loop)
#define TPB_N   2     // node tiles per block (small -> no dispatch tail)

typedef _Float16 f16x8  __attribute__((ext_vector_type(8)));
typedef float    f32x16 __attribute__((ext_vector_type(16)));
typedef int      intx4  __attribute__((ext_vector_type(4)));

// ---------------- generic zero ----------------
__global__ void zero_kernel(float4* __restrict__ p, long long n4) {
    long long idx    = (long long)blockIdx.x * blockDim.x + threadIdx.x;
    long long stride = (long long)gridDim.x * blockDim.x;
    const float4 z = {0.f, 0.f, 0.f, 0.f};
    for (long long i = idx; i < n4; i += stride) p[i] = z;
}

// ---------------- W prep: f16 images in B-fragment order ----------------
// img_m[g*128 + o] (16B = 8 f16) = Wm[o][8g .. 8g+7],  g in [0,32)  (64 KB)
// img_n at +65536 likewise for Wn.
__global__ void prep_w(const float* __restrict__ Wm, const float* __restrict__ Wn,
                       unsigned char* __restrict__ img) {
    int t = blockIdx.x * blockDim.x + threadIdx.x;
    if (t >= 4096) return;
    int g = t >> 7, o = t & 127;
    f16x8 vm, vn;
#pragma unroll
    for (int j = 0; j < 8; ++j) {
        vm[j] = (_Float16)Wm[o * TWO_D + 8 * g + j];
        vn[j] = (_Float16)Wn[o * TWO_D + 8 * g + j];
    }
    ((f16x8*)img)[t]           = vm;
    ((f16x8*)(img + 65536))[t] = vn;
}

// ---------------- counting sort of edges by receiver (proven) ----------
__global__ void hist_kernel(const int* __restrict__ recv, int* __restrict__ counts) {
    int e = blockIdx.x * blockDim.x + threadIdx.x;
    if (e < N_EDGES) atomicAdd(&counts[recv[e]], 1);
}

__global__ __launch_bounds__(1024)
void scan_kernel(const int* __restrict__ counts, int* __restrict__ cursor) {
    __shared__ int tmp[1024];
    int t = threadIdx.x;
    int local[10];
    int s = 0;
#pragma unroll
    for (int j = 0; j < 10; ++j) {
        int idx = t * 10 + j;
        int v = (idx < N_NODES) ? counts[idx] : 0;
        local[j] = s; s += v;
    }
    tmp[t] = s; __syncthreads();
    for (int off = 1; off < 1024; off <<= 1) {
        int v = tmp[t];
        int add = (t >= off) ? tmp[t - off] : 0;
        __syncthreads();
        tmp[t] = v + add;
        __syncthreads();
    }
    int base = (t > 0) ? tmp[t - 1] : 0;
#pragma unroll
    for (int j = 0; j < 10; ++j) {
        int idx = t * 10 + j;
        if (idx < N_NODES) cursor[idx] = base + local[j];
    }
}

__global__ void scatter_kernel(const int* __restrict__ recv, int* __restrict__ cursor,
                               int* __restrict__ perm) {
    int e = blockIdx.x * blockDim.x + threadIdx.x;
    if (e < N_EDGES) {
        int p = atomicAdd(&cursor[recv[e]], 1);
        perm[p] = e;
    }
}

// ---------------- MFMA edge kernel v6 (R9 base + index-only prefetch) ----
// 1-D grid 5000 blocks; batch = bid & 7 (XCD-pinned: FETCH 270->182 MB, R9).
// 256 threads = 4 waves; wave w owns outs [32w,32w+32), W f16 frags pinned
// in regs via asm (resident, R9). Persistent loop over TPB_E sorted tiles.
// PIPELINE (index-only, 1 live int -> no spill): next tile's perm->recv/send
// chain (2 dependent L2 latencies) is issued right after the staging barrier
// and consumed next iteration; only the row loads (1 latency) stay at tile
// start. R10's ROW prefetch (32 VGPRs live across the body) spilled to
// scratch -> 852 MB HBM FETCH; do not reintroduce it.
__global__ __launch_bounds__(256, 4)
void edge_mfma(const float* __restrict__ nodes,
               const unsigned char* __restrict__ wimg,
               const float* __restrict__ bm,
               const float* __restrict__ g1,
               const float* __restrict__ b1,
               const int*   __restrict__ senders,
               const int*   __restrict__ receivers,
               const int*   __restrict__ perm,
               float* __restrict__ inbox) {
    // Xh [0,16K), Xl [16K,32K); msg fp32[32][132] overlays @16384..33280
    __shared__ __align__(16) unsigned char s_lds[33280];
    __shared__ int   s_recv[ETILE];
    __shared__ float s_mu[ETILE];
    __shared__ float s_rs[ETILE];

    const int tid    = threadIdx.x;
    const int b      = blockIdx.x & 7;          // batch == XCD (round-robin)
    const int grp    = blockIdx.x >> 3;         // tile group within batch
    const int w      = tid >> 6;
    const int l      = tid & 63;
    const int lane31 = l & 31;
    const int hiG    = l >> 5;
    const int o      = w * 32 + lane31;         // this lane's output column

    // ---- W fragments -> registers, ONCE, pinned (resident, R9) ----
    intx4 wfi[16];
    {
        const intx4* img = (const intx4*)wimg;
#pragma unroll
        for (int ks = 0; ks < 16; ++ks)
            wfi[ks] = img[(2 * ks + hiG) * 128 + o];
#pragma unroll
        for (int ks = 0; ks < 16; ++ks)
            asm volatile("" : "+v"(wfi[ks]));   // opaque def: must stay resident
    }
    const float bmv = bm[o];
    const int   col  = tid & 127;
    const int   half = tid >> 7;
    const float gv = g1[col], bv = b1[col];
    float* const abase = inbox + (size_t)b * N_NODES * D + col;

    const int i  = tid & 31;   // edge slot
    const int q8 = tid >> 5;   // k chunk [32*q8, 32*q8+32)
    f16x8* const Xh  = (f16x8*)s_lds;
    f16x8* const Xl  = (f16x8*)(s_lds + 16384);
    float* const msg = (float*)(s_lds + 16384);

    // ---- prologue: resolve tile 0's index chain ----
    int rcur;
    {
        const int pe = perm[grp * TPB_E * ETILE + i];
        rcur = (q8 < 4) ? receivers[pe] : senders[pe];
    }

    for (int it = 0; it < TPB_E; ++it) {
        // ---- stage: row loads (1 latency; indices already resolved) ----
        if (q8 == 0) s_recv[i] = rcur;
        {
            const float* row = nodes + ((size_t)b * N_NODES + rcur) * D + (q8 & 3) * 32;
#pragma unroll
            for (int j = 0; j < 4; ++j) {
                const float4 va = *(const float4*)(row + 8 * j);
                const float4 vb = *(const float4*)(row + 8 * j + 4);
                const float xs[8] = {va.x, va.y, va.z, va.w, vb.x, vb.y, vb.z, vb.w};
                f16x8 h, lo;
#pragma unroll
                for (int u = 0; u < 8; ++u) {
                    h[u]  = (_Float16)xs[u];
                    lo[u] = (_Float16)(xs[u] - (float)h[u]);
                }
                const int g = 4 * q8 + j;
                Xh[g * 32 + i] = h;
                Xl[g * 32 + i] = lo;
            }
        }
        __syncthreads();

        // ---- issue next tile's INDEX chain (hides under k-loop+LN+scatter) --
        if (it + 1 < TPB_E) {
            const int pe = perm[(grp * TPB_E + it + 1) * ETILE + i];
            rcur = (q8 < 4) ? receivers[pe] : senders[pe];
        }

        // ---- k-loop: pure LDS-read + MFMA (W already in regs) ----
        f32x16 acc;
#pragma unroll
        for (int r = 0; r < 16; ++r) acc[r] = 0.f;
        __builtin_amdgcn_s_setprio(1);
#pragma unroll
        for (int ks = 0; ks < 16; ++ks) {
            const f16x8 ah = Xh[(2 * ks + hiG) * 32 + lane31];
            const f16x8 al = Xl[(2 * ks + hiG) * 32 + lane31];
            const f16x8 wk = __builtin_bit_cast(f16x8, wfi[ks]);
            acc = __builtin_amdgcn_mfma_f32_32x32x16_f16(ah, wk, acc, 0, 0, 0);
            acc = __builtin_amdgcn_mfma_f32_32x32x16_f16(al, wk, acc, 0, 0, 0);
        }
        __builtin_amdgcn_s_setprio(0);
        __syncthreads();   // X reads done; msg overlays Xl

        // ---- bias + raw messages -> msg[32][132] ----
#pragma unroll
        for (int r = 0; r < 16; ++r) {
            const int m = (r & 3) + 8 * (r >> 2) + 4 * hiG;
            msg[m * 132 + o] = acc[r] + bmv;
        }
        __syncthreads();

        // ---- LN stats, single pass (8 threads per row) ----
        {
            const int m = tid >> 3, c0 = tid & 7;
            float s = 0.f, s2 = 0.f;
#pragma unroll
            for (int i2 = 0; i2 < 16; ++i2) {
                const float v = msg[m * 132 + c0 + 8 * i2];
                s += v; s2 += v * v;
            }
            s  += __shfl_xor(s, 1, 64);  s  += __shfl_xor(s, 2, 64);  s  += __shfl_xor(s, 4, 64);
            s2 += __shfl_xor(s2, 1, 64); s2 += __shfl_xor(s2, 2, 64); s2 += __shfl_xor(s2, 4, 64);
            if (c0 == 0) {
                const float mu  = s * (1.f / 128.f);
                const float var = s2 * (1.f / 128.f) - mu * mu;
                s_mu[m] = mu;
                s_rs[m] = rsqrtf(var + EPS);
            }
        }
        __syncthreads();

        // ---- scatter: inline LN + run-merge over sorted receivers ----
        {
            int prev = -1; float accu = 0.f;
#pragma unroll
            for (int e = 0; e < 16; ++e) {
                const int ee = half * 16 + e;
                const int r  = s_recv[ee];
                const float val = (msg[ee * 132 + col] - s_mu[ee]) * s_rs[ee] * gv + bv;
                if (r != prev) {
                    if (prev >= 0) atomicAdd(abase + (size_t)prev * D, accu);
                    prev = r; accu = val;
                } else {
                    accu += val;
                }
            }
            if (prev >= 0) atomicAdd(abase + (size_t)prev * D, accu);
        }
        __syncthreads();   // protect X/msg before next tile's stage
    }
}

// ---------------- MFMA node kernel v6 (simple staging, TPB_N=2) ----------
__global__ __launch_bounds__(256, 4)
void node_mfma(const float* __restrict__ nodes,
               const float* __restrict__ inbox,
               const unsigned char* __restrict__ wimg,
               const float* __restrict__ bn,
               const float* __restrict__ g2,
               const float* __restrict__ b2,
               float* __restrict__ out) {
    __shared__ __align__(16) unsigned char s_lds[33280];
    __shared__ float s_mu[ETILE];
    __shared__ float s_rs[ETILE];

    const int tid    = threadIdx.x;
    const int b      = blockIdx.x & 7;
    const int grp    = blockIdx.x >> 3;
    const int w      = tid >> 6;
    const int l      = tid & 63;
    const int lane31 = l & 31;
    const int hiG    = l >> 5;
    const int o      = w * 32 + lane31;

    intx4 wfi[16];
    {
        const intx4* img = (const intx4*)wimg;
#pragma unroll
        for (int ks = 0; ks < 16; ++ks)
            wfi[ks] = img[(2 * ks + hiG) * 128 + o];
#pragma unroll
        for (int ks = 0; ks < 16; ++ks)
            asm volatile("" : "+v"(wfi[ks]));
    }
    const float bnv = bn[o];
    const int   col  = tid & 127;
    const int   half = tid >> 7;
    const float gv = g2[col], bv = b2[col];

    const int i  = tid & 31;
    const int q8 = tid >> 5;
    f16x8* const Xh  = (f16x8*)s_lds;
    f16x8* const Xl  = (f16x8*)(s_lds + 16384);
    float* const msg = (float*)(s_lds + 16384);

    const int NTILES = (N_NODES + ETILE - 1) / ETILE;   // 313

    for (int it = 0; it < TPB_N; ++it) {
        const int tile = grp * TPB_N + it;
        if (tile >= NTILES) break;                       // uniform per block
        const int n0 = tile * ETILE;

        {
            int n = n0 + i;
            if (n >= N_NODES) n = N_NODES - 1;           // clamp loads
            const float* row = ((q8 < 4) ? nodes : inbox)
                             + ((size_t)b * N_NODES + n) * D + (q8 & 3) * 32;
#pragma unroll
            for (int j = 0; j < 4; ++j) {
                const float4 va = *(const float4*)(row + 8 * j);
                const float4 vb = *(const float4*)(row + 8 * j + 4);
                const float xs[8] = {va.x, va.y, va.z, va.w, vb.x, vb.y, vb.z, vb.w};
                f16x8 h, lo;
#pragma unroll
                for (int u = 0; u < 8; ++u) {
                    h[u]  = (_Float16)xs[u];
                    lo[u] = (_Float16)(xs[u] - (float)h[u]);
                }
                const int g = 4 * q8 + j;
                Xh[g * 32 + i] = h;
                Xl[g * 32 + i] = lo;
            }
        }
        __syncthreads();

        f32x16 acc;
#pragma unroll
        for (int r = 0; r < 16; ++r) acc[r] = 0.f;
        __builtin_amdgcn_s_setprio(1);
#pragma unroll
        for (int ks = 0; ks < 16; ++ks) {
            const f16x8 ah = Xh[(2 * ks + hiG) * 32 + lane31];
            const f16x8 al = Xl[(2 * ks + hiG) * 32 + lane31];
            const f16x8 wk = __builtin_bit_cast(f16x8, wfi[ks]);
            acc = __builtin_amdgcn_mfma_f32_32x32x16_f16(ah, wk, acc, 0, 0, 0);
            acc = __builtin_amdgcn_mfma_f32_32x32x16_f16(al, wk, acc, 0, 0, 0);
        }
        __builtin_amdgcn_s_setprio(0);
        __syncthreads();

#pragma unroll
        for (int r = 0; r < 16; ++r) {
            const int m = (r & 3) + 8 * (r >> 2) + 4 * hiG;
            msg[m * 132 + o] = acc[r] + bnv;
        }
        __syncthreads();

        {
            const int m = tid >> 3, c0 = tid & 7;
            float s = 0.f, s2 = 0.f;
#pragma unroll
            for (int i2 = 0; i2 < 16; ++i2) {
                const float v = msg[m * 132 + c0 + 8 * i2];
                s += v; s2 += v * v;
            }
            s  += __shfl_xor(s, 1, 64);  s  += __shfl_xor(s, 2, 64);  s  += __shfl_xor(s, 4, 64);
            s2 += __shfl_xor(s2, 1, 64); s2 += __shfl_xor(s2, 2, 64); s2 += __shfl_xor(s2, 4, 64);
            if (c0 == 0) {
                const float mu  = s * (1.f / 128.f);
                const float var = s2 * (1.f / 128.f) - mu * mu;
                s_mu[m] = mu;
                s_rs[m] = rsqrtf(var + EPS);
            }
        }
        __syncthreads();

        {
#pragma unroll
            for (int e = 0; e < 16; ++e) {
                const int ee = half * 16 + e;
                const int n  = n0 + ee;
                if (n < N_NODES) {
                    out[((size_t)b * N_NODES + n) * D + col] =
                        (msg[ee * 132 + col] - s_mu[ee]) * s_rs[ee] * gv + bv;
                }
            }
        }
        __syncthreads();
    }
}

// ---------------- fp32 fallback kernels (proven R2, no workspace) ---------
__global__ __launch_bounds__(256, 2)
void edge_kernel(const float* __restrict__ nodes,
                 const float* __restrict__ Wm,
                 const float* __restrict__ bm,
                 const float* __restrict__ g1,
                 const float* __restrict__ b1,
                 const int*   __restrict__ senders,
                 const int*   __restrict__ receivers,
                 float* __restrict__ inbox) {
    __shared__ __align__(16) float ldsE[TWO_D][36];
    __shared__ __align__(16) float ldsW[64 * D];
    const int tid = threadIdx.x;
    const int b   = blockIdx.y;
    const int e0  = blockIdx.x * 32;
    const float* nb = nodes + (size_t)b * N_NODES * D;
    {
        const int i = tid >> 3, q0 = tid & 7, e = e0 + i;
        const float* rowR = nb + (size_t)receivers[e] * D;
        const float* rowS = nb + (size_t)senders[e] * D;
#pragma unroll
        for (int j = 0; j < 8; ++j) {
            const int k = (j * 8 + q0) * 4;
            const float4 v = (k < D) ? *(const float4*)(rowR + k)
                                     : *(const float4*)(rowS + (k - D));
            ldsE[k + 0][i] = v.x; ldsE[k + 1][i] = v.y;
            ldsE[k + 2][i] = v.z; ldsE[k + 3][i] = v.w;
        }
    }
    float acc[4][4];
#pragma unroll
    for (int a = 0; a < 4; ++a)
#pragma unroll
        for (int c = 0; c < 4; ++c) acc[a][c] = 0.0f;
    const int og = tid & 31, eg = tid >> 5;
    for (int kt = 0; kt < 4; ++kt) {
        __syncthreads();
        {
            const int oo = tid >> 1, half = tid & 1;
            const float* wrow = Wm + oo * TWO_D + kt * 64 + half * 32;
#pragma unroll
            for (int j = 0; j < 8; ++j) {
                const float4 w4 = *(const float4*)(wrow + j * 4);
                const int k2 = half * 32 + j * 4;
                ldsW[(k2 + 0) * D + oo] = w4.x; ldsW[(k2 + 1) * D + oo] = w4.y;
                ldsW[(k2 + 2) * D + oo] = w4.z; ldsW[(k2 + 3) * D + oo] = w4.w;
            }
        }
        __syncthreads();
#pragma unroll 4
        for (int k2 = 0; k2 < 64; ++k2) {
            const float4 wv = *(const float4*)&ldsW[k2 * D + 4 * og];
            const float4 xv = *(const float4*)&ldsE[kt * 64 + k2][4 * eg];
            const float wa[4] = {wv.x, wv.y, wv.z, wv.w};
            const float xa[4] = {xv.x, xv.y, xv.z, xv.w};
#pragma unroll
            for (int a = 0; a < 4; ++a)
#pragma unroll
                for (int c = 0; c < 4; ++c)
                    acc[a][c] = fmaf(xa[a], wa[c], acc[a][c]);
        }
    }
    const float4 bmv = *(const float4*)&bm[4 * og];
    const float4 g1v = *(const float4*)&g1[4 * og];
    const float4 b1v = *(const float4*)&b1[4 * og];
#pragma unroll
    for (int a = 0; a < 4; ++a) {
        acc[a][0] += bmv.x; acc[a][1] += bmv.y;
        acc[a][2] += bmv.z; acc[a][3] += bmv.w;
    }
    float mu[4], rs[4];
#pragma unroll
    for (int a = 0; a < 4; ++a) {
        float s = acc[a][0] + acc[a][1] + acc[a][2] + acc[a][3];
#pragma unroll
        for (int m = 16; m >= 1; m >>= 1) s += __shfl_xor(s, m, 64);
        mu[a] = s * (1.0f / 128.0f);
        const float d0 = acc[a][0] - mu[a], d1 = acc[a][1] - mu[a];
        const float d2 = acc[a][2] - mu[a], d3 = acc[a][3] - mu[a];
        float q = d0 * d0 + d1 * d1 + d2 * d2 + d3 * d3;
#pragma unroll
        for (int m = 16; m >= 1; m >>= 1) q += __shfl_xor(q, m, 64);
        rs[a] = rsqrtf(q * (1.0f / 128.0f) + EPS);
    }
#pragma unroll
    for (int a = 0; a < 4; ++a) {
        const int e = e0 + 4 * eg + a;
        const int r = receivers[e];
        float* dst = inbox + ((size_t)b * N_NODES + r) * D + 4 * og;
        atomicAdd(dst + 0, (acc[a][0] - mu[a]) * rs[a] * g1v.x + b1v.x);
        atomicAdd(dst + 1, (acc[a][1] - mu[a]) * rs[a] * g1v.y + b1v.y);
        atomicAdd(dst + 2, (acc[a][2] - mu[a]) * rs[a] * g1v.z + b1v.z);
        atomicAdd(dst + 3, (acc[a][3] - mu[a]) * rs[a] * g1v.w + b1v.w);
    }
}

__global__ __launch_bounds__(256, 2)
void node_kernel(const float* __restrict__ nodes,
                 const float* __restrict__ inbox,
                 const float* __restrict__ Wn,
                 const float* __restrict__ bn,
                 const float* __restrict__ g2,
                 const float* __restrict__ b2,
                 float* __restrict__ out) {
    __shared__ __align__(16) float ldsE[TWO_D][36];
    __shared__ __align__(16) float ldsW[64 * D];
    const int tid = threadIdx.x;
    const int b   = blockIdx.y;
    const int n0  = blockIdx.x * 32;
    {
        const int i = tid >> 3, q0 = tid & 7;
        int n = n0 + i;
        if (n >= N_NODES) n = N_NODES - 1;
        const float* rowN = nodes + ((size_t)b * N_NODES + n) * D;
        const float* rowI = inbox + ((size_t)b * N_NODES + n) * D;
#pragma unroll
        for (int j = 0; j < 8; ++j) {
            const int k = (j * 8 + q0) * 4;
            const float4 v = (k < D) ? *(const float4*)(rowN + k)
                                     : *(const float4*)(rowI + (k - D));
            ldsE[k + 0][i] = v.x; ldsE[k + 1][i] = v.y;
            ldsE[k + 2][i] = v.z; ldsE[k + 3][i] = v.w;
        }
    }
    float acc[4][4];
#pragma unroll
    for (int a = 0; a < 4; ++a)
#pragma unroll
        for (int c = 0; c < 4; ++c) acc[a][c] = 0.0f;
    const int og = tid & 31, eg = tid >> 5;
    for (int kt = 0; kt < 4; ++kt) {
        __syncthreads();
        {
            const int oo = tid >> 1, half = tid & 1;
            const float* wrow = Wn + oo * TWO_D + kt * 64 + half * 32;
#pragma unroll
            for (int j = 0; j < 8; ++j) {
                const float4 w4 = *(const float4*)(wrow + j * 4);
                const int k2 = half * 32 + j * 4;
                ldsW[(k2 + 0) * D + oo] = w4.x; ldsW[(k2 + 1) * D + oo] = w4.y;
                ldsW[(k2 + 2) * D + oo] = w4.z; ldsW[(k2 + 3) * D + oo] = w4.w;
            }
        }
        __syncthreads();
#pragma unroll 4
        for (int k2 = 0; k2 < 64; ++k2) {
            const float4 wv = *(const float4*)&ldsW[k2 * D + 4 * og];
            const float4 xv = *(const float4*)&ldsE[kt * 64 + k2][4 * eg];
            const float wa[4] = {wv.x, wv.y, wv.z, wv.w};
            const float xa[4] = {xv.x, xv.y, xv.z, xv.w};
#pragma unroll
            for (int a = 0; a < 4; ++a)
#pragma unroll
                for (int c = 0; c < 4; ++c)
                    acc[a][c] = fmaf(xa[a], wa[c], acc[a][c]);
        }
    }
    const float4 bnv = *(const float4*)&bn[4 * og];
    const float4 g2v = *(const float4*)&g2[4 * og];
    const float4 b2v = *(const float4*)&b2[4 * og];
#pragma unroll
    for (int a = 0; a < 4; ++a) {
        acc[a][0] += bnv.x; acc[a][1] += bnv.y;
        acc[a][2] += bnv.z; acc[a][3] += bnv.w;
    }
    float mu[4], rs[4];
#pragma unroll
    for (int a = 0; a < 4; ++a) {
        float s = acc[a][0] + acc[a][1] + acc[a][2] + acc[a][3];
#pragma unroll
        for (int m = 16; m >= 1; m >>= 1) s += __shfl_xor(s, m, 64);
        mu[a] = s * (1.0f / 128.0f);
        const float d0 = acc[a][0] - mu[a], d1 = acc[a][1] - mu[a];
        const float d2 = acc[a][2] - mu[a], d3 = acc[a][3] - mu[a];
        float q = d0 * d0 + d1 * d1 + d2 * d2 + d3 * d3;
#pragma unroll
        for (int m = 16; m >= 1; m >>= 1) q += __shfl_xor(q, m, 64);
        rs[a] = rsqrtf(q * (1.0f / 128.0f) + EPS);
    }
#pragma unroll
    for (int a = 0; a < 4; ++a) {
        const int n = n0 + 4 * eg + a;
        if (n < N_NODES) {
            float4 o4;
            o4.x = (acc[a][0] - mu[a]) * rs[a] * g2v.x + b2v.x;
            o4.y = (acc[a][1] - mu[a]) * rs[a] * g2v.y + b2v.y;
            o4.z = (acc[a][2] - mu[a]) * rs[a] * g2v.z + b2v.z;
            o4.w = (acc[a][3] - mu[a]) * rs[a] * g2v.w + b2v.w;
            *(float4*)(out + ((size_t)b * N_NODES + n) * D + 4 * og) = o4;
        }
    }
}

// ---------------------------------------------------------------------------
extern "C" void kernel_launch(void* const* d_in, const int* in_sizes, int n_in,
                              void* d_out, int out_size, void* d_ws, size_t ws_size,
                              hipStream_t stream) {
    const float* nodes     = (const float*)d_in[0];
    const float* Wm        = (const float*)d_in[1];
    const float* bm        = (const float*)d_in[2];
    const float* g1        = (const float*)d_in[3];
    const float* b1        = (const float*)d_in[4];
    const float* Wn        = (const float*)d_in[5];
    const float* bn        = (const float*)d_in[6];
    const float* g2        = (const float*)d_in[7];
    const float* b2        = (const float*)d_in[8];
    const int*   senders   = (const int*)d_in[9];
    const int*   receivers = (const int*)d_in[10];
    float*       out       = (float*)d_out;

    const long long inbox_n = (long long)BATCH * N_NODES * D;   // 10.24M floats
    // ws: [0,64K) img_m | [64K,128K) img_n | [128K,+720K) sort | [1M,+41MB) inbox
    const size_t SCRATCH_NEED = 131072 + 720128;

    if (d_ws != nullptr && ws_size >= SCRATCH_NEED) {
        unsigned char* wsb  = (unsigned char*)d_ws;
        unsigned char* wimg = wsb;                 // img_m @0, img_n @65536
        int* ints   = (int*)(wsb + 131072);
        int* counts = ints;            // 10000 (16B aligned)
        int* cursor = ints + 10016;    // 10000
        int* perm   = ints + 20032;    // 160000
        float* inbox = (ws_size >= (size_t)1048576 + (size_t)inbox_n * 4)
                           ? (float*)(wsb + 1048576) : out;

        zero_kernel<<<dim3(10),   dim3(256), 0, stream>>>((float4*)counts, 2500);
        zero_kernel<<<dim3(2048), dim3(256), 0, stream>>>((float4*)inbox, inbox_n / 4);
        prep_w<<<dim3(16), dim3(256), 0, stream>>>(Wm, Wn, wimg);
        hist_kernel<<<dim3(625), dim3(256), 0, stream>>>(receivers, counts);
        scan_kernel<<<dim3(1), dim3(1024), 0, stream>>>(counts, cursor);
        scatter_kernel<<<dim3(625), dim3(256), 0, stream>>>(receivers, cursor, perm);

        // 1-D grid, batch = bid & 7 -> XCD-pinned batches (5000 blocks)
        edge_mfma<<<dim3(N_EDGES / ETILE / TPB_E * BATCH), dim3(256), 0, stream>>>(
            nodes, wimg, bm, g1, b1, senders, receivers, perm, inbox);

        // 313 node tiles -> 157 groups x 8 batches = 1256 blocks
        const int ntiles = (N_NODES + ETILE - 1) / ETILE;
        node_mfma<<<dim3((ntiles + TPB_N - 1) / TPB_N * BATCH), dim3(256), 0, stream>>>(
            nodes, inbox, wimg + 65536, bn, g2, b2, out);
    } else {
        // proven fp32 fallback (no workspace needed)
        float* inbox = out;
        zero_kernel<<<dim3(2048), dim3(256), 0, stream>>>((float4*)inbox, inbox_n / 4);
        edge_kernel<<<dim3(N_EDGES / 32, BATCH), dim3(256), 0, stream>>>(
            nodes, Wm, bm, g1, b1, senders, receivers, inbox);
        node_kernel<<<dim3((N_NODES + 31) / 32, BATCH), dim3(256), 0, stream>>>(
            nodes, inbox, Wn, bn, g2, b2, out);
    }
}